// Round 5
// baseline (259.154 us; speedup 1.0000x reference)
//
#include <hip/hip_runtime.h>

// Problem constants (B=1 fixed by reference)
#define HW_TOTAL (480 * 640)           // 307200 pixels
#define NC 12                           // output channels (C-1)
#define VOX_TOTAL_C (240 * 144 * 240)   // 8,294,400 voxels (divisible by 32)

#define REC_STRIDE 16                   // floats per voxel record (64 B line)

typedef float f32x4 __attribute__((ext_vector_type(4)));

// ---------------------------------------------------------------------------
// k1 (after 1 MB bitmap memset): scatter pixel records.
// x reads are pixel-indexed -> coalesced across lanes (no transpose needed).
// rec[v] gets all 12 channels + 16B pad as four float4 stores = one full
// 64-B line -> no write-allocate RMW. bitmap bit set via atomicOr
// (commutative -> deterministic; map values unique -> no rec conflicts).
__global__ void scatter_rec_kernel(const float* __restrict__ x,
                                   const int* __restrict__ map,
                                   float* __restrict__ rec,
                                   unsigned int* __restrict__ bitmap) {
    int p = blockIdx.x * blockDim.x + threadIdx.x;
    if (p >= HW_TOTAL) return;
    int v = map[p];
    if (v <= 0) return;                 // invalid pixel (dropped)
    float vals[NC];
#pragma unroll
    for (int c = 0; c < NC; ++c)
        vals[c] = x[(size_t)(c + 1) * HW_TOTAL + p];
    f32x4* dst = (f32x4*)(rec + (size_t)v * REC_STRIDE);
    f32x4 a = {vals[0], vals[1], vals[2],  vals[3]};
    f32x4 b = {vals[4], vals[5], vals[6],  vals[7]};
    f32x4 c4 = {vals[8], vals[9], vals[10], vals[11]};
    f32x4 z = {0.f, 0.f, 0.f, 0.f};
    dst[0] = a; dst[1] = b; dst[2] = c4; dst[3] = z;   // full 64-B line
    atomicOr(&bitmap[v >> 5], 1u << (v & 31));
}

// ---------------------------------------------------------------------------
// k2: streaming gather. 4 voxels/thread. Bitmap nibble gates the (rare, 13%)
// record reads; record reads are voxel-sequential (no pointer chase).
// All out stores nontemporal (398 MB stream, keep L2 for rec/bitmap).
__global__ void gather_rec_kernel(const float* __restrict__ rec,
                                  const unsigned int* __restrict__ bitmap,
                                  float* __restrict__ out) {
    int t = blockIdx.x * blockDim.x + threadIdx.x;   // 4-voxel group
    if (t >= VOX_TOTAL_C / 4) return;
    unsigned int word = bitmap[t >> 3];              // 8 lanes share a word
    unsigned int nib = (word >> ((t & 7) * 4)) & 0xFu;
    size_t base = (size_t)t * 4;
    if (nib == 0) {                                  // ~87% of threads
        const f32x4 z = {0.f, 0.f, 0.f, 0.f};
#pragma unroll
        for (int c = 0; c < NC; ++c)
            __builtin_nontemporal_store(z, (f32x4*)(out + (size_t)c * VOX_TOTAL_C + base));
        return;
    }
    f32x4 A[4][3];
#pragma unroll
    for (int k = 0; k < 4; ++k) {
        if (nib & (1u << k)) {
            const f32x4* r = (const f32x4*)(rec + (base + (size_t)k) * REC_STRIDE);
            A[k][0] = r[0]; A[k][1] = r[1]; A[k][2] = r[2];
        } else {
            f32x4 z = {0.f, 0.f, 0.f, 0.f};
            A[k][0] = z; A[k][1] = z; A[k][2] = z;
        }
    }
#pragma unroll
    for (int c = 0; c < NC; ++c) {
        f32x4 o = { A[0][c >> 2][c & 3], A[1][c >> 2][c & 3],
                    A[2][c >> 2][c & 3], A[3][c >> 2][c & 3] };
        __builtin_nontemporal_store(o, (f32x4*)(out + (size_t)c * VOX_TOTAL_C + base));
    }
}

// ---------------------------------------------------------------------------
// Fallback (only if ws_size were too small): memset + naive scatter (R1 path).
__global__ void naive_scatter_kernel(const float* __restrict__ x,
                                     const int* __restrict__ map,
                                     float* __restrict__ out) {
    int p = blockIdx.x * blockDim.x + threadIdx.x;
    if (p >= HW_TOTAL) return;
    int v = map[p];
    if (v <= 0) return;
#pragma unroll
    for (int c = 0; c < NC; ++c)
        out[(size_t)c * VOX_TOTAL_C + (size_t)v] = x[(size_t)(c + 1) * HW_TOTAL + p];
}

extern "C" void kernel_launch(void* const* d_in, const int* in_sizes, int n_in,
                              void* d_out, int out_size, void* d_ws, size_t ws_size,
                              hipStream_t stream) {
    const float* x = (const float*)d_in[0];      // (1, 13, 480, 640) f32
    const int* map = (const int*)d_in[1];        // (1, 307200) i32
    float* out = (float*)d_out;                  // (1, 12, 240, 144, 240) f32

    const size_t rec_bytes = (size_t)VOX_TOTAL_C * REC_STRIDE * sizeof(float); // 531 MB
    const size_t bitmap_bytes = VOX_TOTAL_C / 8;                               // 1.04 MB

    if (ws_size < rec_bytes + bitmap_bytes) {
        // Safety net (ws is ~1.59 GB in this harness; shouldn't trigger).
        hipMemsetAsync(out, 0, (size_t)NC * VOX_TOTAL_C * sizeof(float), stream);
        naive_scatter_kernel<<<HW_TOTAL / 256, 256, 0, stream>>>(x, map, out);
        return;
    }

    float* rec = (float*)d_ws;
    unsigned int* bitmap = (unsigned int*)((char*)d_ws + rec_bytes);

    // Zero only the bitmap (1 MB) every call; rec is gated by bitmap bits.
    hipMemsetAsync(bitmap, 0, bitmap_bytes, stream);

    scatter_rec_kernel<<<HW_TOTAL / 256, 256, 0, stream>>>(x, map, rec, bitmap);

    const int total = VOX_TOTAL_C / 4;               // 2,073,600 threads
    gather_rec_kernel<<<(total + 255) / 256, 256, 0, stream>>>(rec, bitmap, out);
}

// Round 6
// 103.681 us; speedup vs baseline: 2.4995x; 2.4995x over previous
//
#include <hip/hip_runtime.h>

// Problem constants (B=1 fixed by reference)
#define HW_TOTAL (480 * 640)           // 307200 pixels
#define NC 12                           // output channels (C-1)
#define VOX_TOTAL_C (240 * 144 * 240)   // 8,294,400 voxels (divisible by 32)

#define REC_STRIDE 16                   // floats per voxel record (64 B line)

typedef float f32x4 __attribute__((ext_vector_type(4)));

// ---------------------------------------------------------------------------
// k1 (after 1 MB bitmap memset): scatter pixel records.
// x reads are pixel-indexed -> coalesced across lanes. rec[v] gets all 12
// channels + 16B pad as four float4 stores = one full 64-B line -> no
// write-allocate RMW. bitmap bit via atomicOr (map values unique -> no rec
// conflicts; atomicOr commutative -> deterministic).
__global__ void scatter_rec_kernel(const float* __restrict__ x,
                                   const int* __restrict__ map,
                                   float* __restrict__ rec,
                                   unsigned int* __restrict__ bitmap) {
    int p = blockIdx.x * blockDim.x + threadIdx.x;
    if (p >= HW_TOTAL) return;
    int v = map[p];
    if (v <= 0) return;                 // invalid pixel (dropped)
    float vals[NC];
#pragma unroll
    for (int c = 0; c < NC; ++c)
        vals[c] = x[(size_t)(c + 1) * HW_TOTAL + p];
    f32x4* dst = (f32x4*)(rec + (size_t)v * REC_STRIDE);
    f32x4 a = {vals[0], vals[1], vals[2],  vals[3]};
    f32x4 b = {vals[4], vals[5], vals[6],  vals[7]};
    f32x4 c4 = {vals[8], vals[9], vals[10], vals[11]};
    f32x4 z = {0.f, 0.f, 0.f, 0.f};
    dst[0] = a; dst[1] = b; dst[2] = c4; dst[3] = z;   // full 64-B line
    atomicOr(&bitmap[v >> 5], 1u << (v & 31));
}

// ---------------------------------------------------------------------------
// k2: streaming gather. 4 voxels/thread. Loads gated on bitmap nibble (rare,
// ~13% of threads; FETCH at line granularity = ~18 MB). Stores are a SINGLE
// unconditional path: all 64 lanes execute the same 12 NT stores -> every
// store instruction covers 1024 B of full 64-B lines (R5's divergent
// dual-path stores caused partial-line NT writes: +21% WRITE_SIZE, 3x BW
// loss). NT keeps the 398 MB stream out of L2, preserving it for rec/bitmap.
__global__ void gather_rec_kernel(const float* __restrict__ rec,
                                  const unsigned int* __restrict__ bitmap,
                                  float* __restrict__ out) {
    int t = blockIdx.x * blockDim.x + threadIdx.x;   // 4-voxel group
    if (t >= VOX_TOTAL_C / 4) return;
    unsigned int word = bitmap[t >> 3];              // 8 lanes share a word
    unsigned int nib = (word >> ((t & 7) * 4)) & 0xFu;
    size_t base = (size_t)t * 4;

    f32x4 A[4][3];
    const f32x4 z = {0.f, 0.f, 0.f, 0.f};
#pragma unroll
    for (int k = 0; k < 4; ++k) {
        A[k][0] = z; A[k][1] = z; A[k][2] = z;
    }
    if (nib) {                                       // rare: gated loads only
#pragma unroll
        for (int k = 0; k < 4; ++k) {
            if (nib & (1u << k)) {
                const f32x4* r = (const f32x4*)(rec + (base + (size_t)k) * REC_STRIDE);
                A[k][0] = r[0]; A[k][1] = r[1]; A[k][2] = r[2];
            }
        }
    }
    // Single unconditional store path — full-line NT writes.
#pragma unroll
    for (int c = 0; c < NC; ++c) {
        f32x4 o = { A[0][c >> 2][c & 3], A[1][c >> 2][c & 3],
                    A[2][c >> 2][c & 3], A[3][c >> 2][c & 3] };
        __builtin_nontemporal_store(o, (f32x4*)(out + (size_t)c * VOX_TOTAL_C + base));
    }
}

// ---------------------------------------------------------------------------
// Fallback (only if ws_size were too small): memset + naive scatter (R1 path).
__global__ void naive_scatter_kernel(const float* __restrict__ x,
                                     const int* __restrict__ map,
                                     float* __restrict__ out) {
    int p = blockIdx.x * blockDim.x + threadIdx.x;
    if (p >= HW_TOTAL) return;
    int v = map[p];
    if (v <= 0) return;
#pragma unroll
    for (int c = 0; c < NC; ++c)
        out[(size_t)c * VOX_TOTAL_C + (size_t)v] = x[(size_t)(c + 1) * HW_TOTAL + p];
}

extern "C" void kernel_launch(void* const* d_in, const int* in_sizes, int n_in,
                              void* d_out, int out_size, void* d_ws, size_t ws_size,
                              hipStream_t stream) {
    const float* x = (const float*)d_in[0];      // (1, 13, 480, 640) f32
    const int* map = (const int*)d_in[1];        // (1, 307200) i32
    float* out = (float*)d_out;                  // (1, 12, 240, 144, 240) f32

    const size_t rec_bytes = (size_t)VOX_TOTAL_C * REC_STRIDE * sizeof(float); // 531 MB
    const size_t bitmap_bytes = VOX_TOTAL_C / 8;                               // 1.04 MB

    if (ws_size < rec_bytes + bitmap_bytes) {
        // Safety net (ws is ~1.59 GB in this harness; shouldn't trigger).
        hipMemsetAsync(out, 0, (size_t)NC * VOX_TOTAL_C * sizeof(float), stream);
        naive_scatter_kernel<<<HW_TOTAL / 256, 256, 0, stream>>>(x, map, out);
        return;
    }

    float* rec = (float*)d_ws;
    unsigned int* bitmap = (unsigned int*)((char*)d_ws + rec_bytes);

    // Zero only the bitmap (1 MB) every call; rec is gated by bitmap bits.
    hipMemsetAsync(bitmap, 0, bitmap_bytes, stream);

    scatter_rec_kernel<<<HW_TOTAL / 256, 256, 0, stream>>>(x, map, rec, bitmap);

    const int total = VOX_TOTAL_C / 4;               // 2,073,600 threads
    gather_rec_kernel<<<(total + 255) / 256, 256, 0, stream>>>(rec, bitmap, out);
}